// Round 1
// baseline (605.514 us; speedup 1.0000x reference)
//
#include <hip/hip_runtime.h>
#include <math.h>

#define Bn 8
#define Tn 2048
#define En 1024
#define Hn 128
#define SQRTH 11.313708498984761f

typedef __attribute__((ext_vector_type(8))) short short8;
typedef __attribute__((ext_vector_type(4))) short short4v;
typedef __attribute__((ext_vector_type(4))) float float4v;

#define MFMA16(a, b, c) __builtin_amdgcn_mfma_f32_16x16x32_bf16((a), (b), (c), 0, 0, 0)

static __device__ __forceinline__ unsigned short f2bf(float f) {
    unsigned u = __float_as_uint(f);
    u += 0x7FFFu + ((u >> 16) & 1u);   // RNE
    return (unsigned short)(u >> 16);
}
static __device__ __forceinline__ float bf2f(unsigned short h) {
    return __uint_as_float(((unsigned)h) << 16);
}

// ---------------------------------------------------------------------------
// Kernel 0: transpose W (E,H) fp32 -> Wt (H,E) split bf16 (hi/lo)
// ---------------------------------------------------------------------------
__global__ __launch_bounds__(256) void wtrans_kernel(
    const float* __restrict__ Wq, const float* __restrict__ Wk, const float* __restrict__ Wv,
    unsigned short* __restrict__ wt_hi, unsigned short* __restrict__ wt_lo)
{
    int z = blockIdx.y;                       // 0=q 1=k 2=v
    const float* W = (z == 0) ? Wq : ((z == 1) ? Wk : Wv);
    int idx = blockIdx.x * 256 + threadIdx.x; // grid.x = 512 -> 131072
    int e = idx >> 7;
    int h = idx & 127;
    float v = W[idx];
    unsigned short hi = f2bf(v);
    unsigned short lo = f2bf(v - bf2f(hi));
    size_t o = (size_t)z * (Hn * En) + (size_t)h * En + e;
    wt_hi[o] = hi;
    wt_lo[o] = lo;
}

// ---------------------------------------------------------------------------
// Kernel 1: projections. block=256 (4 waves), tile 64 rows x 128 cols.
// z=0 -> q (split hi/lo), z=1 -> k (split), z=2 -> v (bf16, stored (B,H,T))
// ---------------------------------------------------------------------------
__global__ __launch_bounds__(256) void proj_kernel(
    const float* __restrict__ x,
    const unsigned short* __restrict__ wt_hi, const unsigned short* __restrict__ wt_lo,
    unsigned short* __restrict__ q_hi, unsigned short* __restrict__ q_lo,
    unsigned short* __restrict__ k_hi, unsigned short* __restrict__ k_lo,
    unsigned short* __restrict__ vT)
{
    int z = blockIdx.y;
    int tid = threadIdx.x;
    int wave = tid >> 6, lane = tid & 63;
    int c15 = lane & 15, kg = lane >> 4;
    int row_m = blockIdx.x * 64 + wave * 16 + c15;     // A-fragment row
    const float* xrow = x + (size_t)row_m * En;
    const unsigned short* wh = wt_hi + (size_t)z * (Hn * En);
    const unsigned short* wl = wt_lo + (size_t)z * (Hn * En);

    float4v acc[8];
#pragma unroll
    for (int i = 0; i < 8; i++) acc[i] = (float4v)0.0f;

    for (int kk = 0; kk < En; kk += 32) {
        const float* ap = xrow + kk + kg * 8;
        float4v f0 = *(const float4v*)ap;
        float4v f1 = *(const float4v*)(ap + 4);
        short8 ah, al;
#pragma unroll
        for (int j = 0; j < 4; j++) {
            unsigned short h0 = f2bf(f0[j]);
            ah[j] = (short)h0; al[j] = (short)f2bf(f0[j] - bf2f(h0));
            unsigned short h1 = f2bf(f1[j]);
            ah[j + 4] = (short)h1; al[j + 4] = (short)f2bf(f1[j] - bf2f(h1));
        }
        if (z < 2) {
#pragma unroll
            for (int nt = 0; nt < 8; nt++) {
                size_t bo = (size_t)(nt * 16 + c15) * En + kk + kg * 8;
                short8 bh = *(const short8*)(wh + bo);
                short8 bl = *(const short8*)(wl + bo);
                acc[nt] = MFMA16(ah, bh, acc[nt]);
                acc[nt] = MFMA16(ah, bl, acc[nt]);
                acc[nt] = MFMA16(al, bh, acc[nt]);
            }
        } else {
#pragma unroll
            for (int nt = 0; nt < 8; nt++) {
                size_t bo = (size_t)(nt * 16 + c15) * En + kk + kg * 8;
                short8 bh = *(const short8*)(wh + bo);
                acc[nt] = MFMA16(ah, bh, acc[nt]);
            }
        }
    }

    int t_base = blockIdx.x * 64 + wave * 16 + kg * 4;   // C/D rows
    if (z < 2) {
        unsigned short* oh = (z == 0) ? q_hi : k_hi;
        unsigned short* ol = (z == 0) ? q_lo : k_lo;
#pragma unroll
        for (int nt = 0; nt < 8; nt++) {
            int h = nt * 16 + c15;
#pragma unroll
            for (int r = 0; r < 4; r++) {
                float v = acc[nt][r];
                unsigned short hh = f2bf(v);
                unsigned short ll = f2bf(v - bf2f(hh));
                size_t o = (size_t)(t_base + r) * Hn + h;
                oh[o] = hh;
                ol[o] = ll;
            }
        }
    } else {
        int b = t_base >> 11;
        int t0 = t_base & 2047;
#pragma unroll
        for (int nt = 0; nt < 8; nt++) {
            int h = nt * 16 + c15;
            short4v pk;
#pragma unroll
            for (int r = 0; r < 4; r++) pk[r] = (short)f2bf(acc[nt][r]);
            *(short4v*)(vT + ((size_t)b * Hn + h) * Tn + t0) = pk;
        }
    }
}

// ---------------------------------------------------------------------------
// Kernel 2: column softmax stats. att^T[s,t] = sqrtH * k[s].q[t].
// One wave per 16 s-rows; online (m,l) over t; butterfly merge over 16 lanes.
// ---------------------------------------------------------------------------
__global__ __launch_bounds__(256) void stats_kernel(
    const unsigned short* __restrict__ q_hi, const unsigned short* __restrict__ q_lo,
    const unsigned short* __restrict__ k_hi, const unsigned short* __restrict__ k_lo,
    float* __restrict__ m_st, float* __restrict__ il_st)
{
    int tid = threadIdx.x;
    int wid = blockIdx.x * 4 + (tid >> 6);   // 0..1023
    int lane = tid & 63;
    int c15 = lane & 15, kg = lane >> 4;
    int b = wid >> 7;
    int s_base = (wid & 127) * 16;

    // A fragments: k rows (persist whole kernel)
    short8 a_h[4], a_l[4];
    {
        int s = s_base + c15;
        const unsigned short* kr = k_hi + ((size_t)(b * Tn + s)) * Hn + kg * 8;
        const unsigned short* krl = k_lo + ((size_t)(b * Tn + s)) * Hn + kg * 8;
#pragma unroll
        for (int st = 0; st < 4; st++) {
            a_h[st] = *(const short8*)(kr + st * 32);
            a_l[st] = *(const short8*)(krl + st * 32);
        }
    }
    float m[4], l[4];
#pragma unroll
    for (int r = 0; r < 4; r++) { m[r] = -3.0e38f; l[r] = 0.0f; }

    for (int tt = s_base; tt < Tn; tt += 16) {
        int t = tt + c15;   // this lane's column (n index)
        const unsigned short* qr = q_hi + ((size_t)(b * Tn + t)) * Hn + kg * 8;
        const unsigned short* qrl = q_lo + ((size_t)(b * Tn + t)) * Hn + kg * 8;
        float4v acc1 = (float4v)0.0f, acc2 = (float4v)0.0f, acc3 = (float4v)0.0f;
#pragma unroll
        for (int st = 0; st < 4; st++) {
            short8 bh = *(const short8*)(qr + st * 32);
            short8 bl = *(const short8*)(qrl + st * 32);
            acc1 = MFMA16(a_h[st], bh, acc1);
            acc2 = MFMA16(a_h[st], bl, acc2);
            acc3 = MFMA16(a_l[st], bh, acc3);
        }
#pragma unroll
        for (int r = 0; r < 4; r++) {
            float attv = (acc1[r] + acc2[r] + acc3[r]) * SQRTH;
            int s_row = s_base + kg * 4 + r;
            bool valid = (t >= s_row);
            float cand = valid ? attv : -3.0e38f;
            float mn = fmaxf(m[r], cand);
            l[r] = l[r] * __expf(m[r] - mn) + (valid ? __expf(attv - mn) : 0.0f);
            m[r] = mn;
        }
    }
    // merge t-subsets across the 16 lanes sharing kg
#pragma unroll
    for (int mask = 1; mask < 16; mask <<= 1) {
#pragma unroll
        for (int r = 0; r < 4; r++) {
            float mo = __shfl_xor(m[r], mask);
            float lo2 = __shfl_xor(l[r], mask);
            float mn = fmaxf(m[r], mo);
            l[r] = l[r] * __expf(m[r] - mn) + lo2 * __expf(mo - mn);
            m[r] = mn;
        }
    }
    if (c15 == 0) {
#pragma unroll
        for (int r = 0; r < 4; r++) {
            int s = s_base + kg * 4 + r;
            m_st[b * Tn + s] = m[r];
            il_st[b * Tn + s] = 1.0f / l[r];
        }
    }
}

// ---------------------------------------------------------------------------
// Kernel 3: output. Wave owns 16 t-rows x all H. Iterate s in steps of 32:
// recompute att (split MFMA), p = exp(att-m_s)/l_s (bf16), LDS C->A layout
// round-trip, PV MFMA with v^T fragments from global.
// block = 128 threads (2 waves); grid (64, B); heavy blocks first.
// ---------------------------------------------------------------------------
__global__ __launch_bounds__(128) void out_kernel(
    const unsigned short* __restrict__ q_hi, const unsigned short* __restrict__ q_lo,
    const unsigned short* __restrict__ k_hi, const unsigned short* __restrict__ k_lo,
    const unsigned short* __restrict__ vT,
    const float* __restrict__ m_st, const float* __restrict__ il_st,
    float* __restrict__ out)
{
    __shared__ __align__(16) unsigned short pbuf[2][16][40];
    int tid = threadIdx.x;
    int wave = tid >> 6, lane = tid & 63;
    int c15 = lane & 15, kg = lane >> 4;
    int b = blockIdx.y;
    int xr = (int)gridDim.x - 1 - (int)blockIdx.x;   // heavy work dispatched first
    int t_base = xr * 32 + wave * 16;

    // A fragments: q rows (persist)
    short8 qa_h[4], qa_l[4];
    {
        int t = t_base + c15;
        const unsigned short* qr = q_hi + ((size_t)(b * Tn + t)) * Hn + kg * 8;
        const unsigned short* qrl = q_lo + ((size_t)(b * Tn + t)) * Hn + kg * 8;
#pragma unroll
        for (int st = 0; st < 4; st++) {
            qa_h[st] = *(const short8*)(qr + st * 32);
            qa_l[st] = *(const short8*)(qrl + st * 32);
        }
    }
    float4v oacc[8];
#pragma unroll
    for (int i = 0; i < 8; i++) oacc[i] = (float4v)0.0f;

    int ns = (t_base + 15) / 32 + 1;
    for (int ss = 0; ss < ns; ss++) {
        int s0 = ss * 32;
#pragma unroll
        for (int half = 0; half < 2; half++) {
            int s16 = s0 + half * 16;
            int s = s16 + c15;
            const unsigned short* kr = k_hi + ((size_t)(b * Tn + s)) * Hn + kg * 8;
            const unsigned short* krl = k_lo + ((size_t)(b * Tn + s)) * Hn + kg * 8;
            float4v acc1 = (float4v)0.0f, acc2 = (float4v)0.0f, acc3 = (float4v)0.0f;
#pragma unroll
            for (int st = 0; st < 4; st++) {
                short8 bh = *(const short8*)(kr + st * 32);
                short8 bl = *(const short8*)(krl + st * 32);
                acc1 = MFMA16(qa_h[st], bh, acc1);
                acc2 = MFMA16(qa_h[st], bl, acc2);
                acc3 = MFMA16(qa_l[st], bh, acc3);
            }
            float msv = m_st[b * Tn + s16 + c15];
            float ilv = il_st[b * Tn + s16 + c15];
#pragma unroll
            for (int r = 0; r < 4; r++) {
                int t = t_base + kg * 4 + r;
                float attv = (acc1[r] + acc2[r] + acc3[r]) * SQRTH;
                float p = (t >= s16 + c15) ? __expf(attv - msv) * ilv : 0.0f;
                pbuf[wave][kg * 4 + r][c15 + half * 16] = f2bf(p);
            }
        }
        // C-layout -> A-layout via LDS (wave-internal, DS pipe is in-order)
        short8 pa = *(const short8*)&pbuf[wave][c15][kg * 8];
#pragma unroll
        for (int nt = 0; nt < 8; nt++) {
            int h = nt * 16 + c15;
            short8 vb = *(const short8*)(vT + ((size_t)(b * Hn + h)) * Tn + s0 + kg * 8);
            oacc[nt] = MFMA16(pa, vb, oacc[nt]);
        }
    }
#pragma unroll
    for (int nt = 0; nt < 8; nt++) {
        int h = nt * 16 + c15;
#pragma unroll
        for (int r = 0; r < 4; r++) {
            int t = t_base + kg * 4 + r;
            out[((size_t)b * Tn + t) * Hn + h] = oacc[nt][r];
        }
    }
}

// ---------------------------------------------------------------------------
extern "C" void kernel_launch(void* const* d_in, const int* in_sizes, int n_in,
                              void* d_out, int out_size, void* d_ws, size_t ws_size,
                              hipStream_t stream)
{
    (void)in_sizes; (void)n_in; (void)out_size; (void)ws_size;
    const float* x  = (const float*)d_in[0];
    const float* Wk = (const float*)d_in[1];
    const float* Wq = (const float*)d_in[2];
    const float* Wv = (const float*)d_in[3];
    float* out = (float*)d_out;

    const size_t NQ = (size_t)Bn * Tn * Hn;        // 2,097,152
    unsigned short* q_hi = (unsigned short*)d_ws;
    unsigned short* q_lo = q_hi + NQ;
    unsigned short* k_hi = q_lo + NQ;
    unsigned short* k_lo = k_hi + NQ;
    unsigned short* vT   = k_lo + NQ;
    unsigned short* wt_hi = vT + NQ;
    unsigned short* wt_lo = wt_hi + (size_t)3 * Hn * En;
    float* m_st  = (float*)(wt_lo + (size_t)3 * Hn * En);
    float* il_st = m_st + (size_t)Bn * Tn;
    // total ws use: ~21.6 MB

    wtrans_kernel<<<dim3(512, 3), 256, 0, stream>>>(Wq, Wk, Wv, wt_hi, wt_lo);
    proj_kernel<<<dim3(256, 3), 256, 0, stream>>>(x, wt_hi, wt_lo, q_hi, q_lo, k_hi, k_lo, vT);
    stats_kernel<<<dim3(256), 256, 0, stream>>>(q_hi, q_lo, k_hi, k_lo, m_st, il_st);
    out_kernel<<<dim3(64, Bn), 128, 0, stream>>>(q_hi, q_lo, k_hi, k_lo, vT, m_st, il_st, out);
}

// Round 2
// 521.118 us; speedup vs baseline: 1.1620x; 1.1620x over previous
//
#include <hip/hip_runtime.h>
#include <math.h>

#define Bn 8
#define Tn 2048
#define En 1024
#define Hn 128
#define SQRTH 11.313708498984761f

typedef __attribute__((ext_vector_type(8))) short short8;
typedef __attribute__((ext_vector_type(4))) short short4v;
typedef __attribute__((ext_vector_type(4))) float float4v;

#define MFMA16(a, b, c) __builtin_amdgcn_mfma_f32_16x16x32_bf16((a), (b), (c), 0, 0, 0)

static __device__ __forceinline__ unsigned short f2bf(float f) {
    unsigned u = __float_as_uint(f);
    u += 0x7FFFu + ((u >> 16) & 1u);   // RNE
    return (unsigned short)(u >> 16);
}
static __device__ __forceinline__ float bf2f(unsigned short h) {
    return __uint_as_float(((unsigned)h) << 16);
}

// ---------------------------------------------------------------------------
// Kernel 0: transpose W (E,H) fp32 -> Wt (H,E) split bf16 (hi/lo)
// ---------------------------------------------------------------------------
__global__ __launch_bounds__(256) void wtrans_kernel(
    const float* __restrict__ Wq, const float* __restrict__ Wk, const float* __restrict__ Wv,
    unsigned short* __restrict__ wt_hi, unsigned short* __restrict__ wt_lo)
{
    int z = blockIdx.y;                       // 0=q 1=k 2=v
    const float* W = (z == 0) ? Wq : ((z == 1) ? Wk : Wv);
    int idx = blockIdx.x * 256 + threadIdx.x; // grid.x = 512 -> 131072
    int e = idx >> 7;
    int h = idx & 127;
    float v = W[idx];
    unsigned short hi = f2bf(v);
    unsigned short lo = f2bf(v - bf2f(hi));
    size_t o = (size_t)z * (Hn * En) + (size_t)h * En + e;
    wt_hi[o] = hi;
    wt_lo[o] = lo;
}

// ---------------------------------------------------------------------------
// Kernel 1: projections. block=256 (4 waves), tile 64 rows x 128 cols.
// z=0 -> q (split hi/lo), z=1 -> k (split), z=2 -> v (bf16, stored (B,H,T))
// ---------------------------------------------------------------------------
__global__ __launch_bounds__(256) void proj_kernel(
    const float* __restrict__ x,
    const unsigned short* __restrict__ wt_hi, const unsigned short* __restrict__ wt_lo,
    unsigned short* __restrict__ q_hi, unsigned short* __restrict__ q_lo,
    unsigned short* __restrict__ k_hi, unsigned short* __restrict__ k_lo,
    unsigned short* __restrict__ vT)
{
    int z = blockIdx.y;
    int tid = threadIdx.x;
    int wave = tid >> 6, lane = tid & 63;
    int c15 = lane & 15, kg = lane >> 4;
    int row_m = blockIdx.x * 64 + wave * 16 + c15;     // A-fragment row
    const float* xrow = x + (size_t)row_m * En;
    const unsigned short* wh = wt_hi + (size_t)z * (Hn * En);
    const unsigned short* wl = wt_lo + (size_t)z * (Hn * En);

    float4v acc[8];
#pragma unroll
    for (int i = 0; i < 8; i++) acc[i] = (float4v)0.0f;

    for (int kk = 0; kk < En; kk += 32) {
        const float* ap = xrow + kk + kg * 8;
        float4v f0 = *(const float4v*)ap;
        float4v f1 = *(const float4v*)(ap + 4);
        short8 ah, al;
#pragma unroll
        for (int j = 0; j < 4; j++) {
            unsigned short h0 = f2bf(f0[j]);
            ah[j] = (short)h0; al[j] = (short)f2bf(f0[j] - bf2f(h0));
            unsigned short h1 = f2bf(f1[j]);
            ah[j + 4] = (short)h1; al[j + 4] = (short)f2bf(f1[j] - bf2f(h1));
        }
        if (z < 2) {
#pragma unroll
            for (int nt = 0; nt < 8; nt++) {
                size_t bo = (size_t)(nt * 16 + c15) * En + kk + kg * 8;
                short8 bh = *(const short8*)(wh + bo);
                short8 bl = *(const short8*)(wl + bo);
                acc[nt] = MFMA16(ah, bh, acc[nt]);
                acc[nt] = MFMA16(ah, bl, acc[nt]);
                acc[nt] = MFMA16(al, bh, acc[nt]);
            }
        } else {
#pragma unroll
            for (int nt = 0; nt < 8; nt++) {
                size_t bo = (size_t)(nt * 16 + c15) * En + kk + kg * 8;
                short8 bh = *(const short8*)(wh + bo);
                acc[nt] = MFMA16(ah, bh, acc[nt]);
            }
        }
    }

    int t_base = blockIdx.x * 64 + wave * 16 + kg * 4;   // C/D rows
    if (z < 2) {
        unsigned short* oh = (z == 0) ? q_hi : k_hi;
        unsigned short* ol = (z == 0) ? q_lo : k_lo;
#pragma unroll
        for (int nt = 0; nt < 8; nt++) {
            int h = nt * 16 + c15;
#pragma unroll
            for (int r = 0; r < 4; r++) {
                float v = acc[nt][r];
                unsigned short hh = f2bf(v);
                unsigned short ll = f2bf(v - bf2f(hh));
                size_t o = (size_t)(t_base + r) * Hn + h;
                oh[o] = hh;
                ol[o] = ll;
            }
        }
    } else {
        int b = t_base >> 11;
        int t0 = t_base & 2047;
#pragma unroll
        for (int nt = 0; nt < 8; nt++) {
            int h = nt * 16 + c15;
            short4v pk;
#pragma unroll
            for (int r = 0; r < 4; r++) pk[r] = (short)f2bf(acc[nt][r]);
            *(short4v*)(vT + ((size_t)b * Hn + h) * Tn + t0) = pk;
        }
    }
}

// ---------------------------------------------------------------------------
// Kernel 2: column softmax stats. att^T[s,t] = sqrtH * k[s].q[t].
// Block (4 waves) per 16 s-rows; waves split the t-loop 4-way (stride 64);
// intra-wave butterfly merge over 16 lanes, then 4-way LDS merge.
// grid (128, B). Low s_base = most work = dispatched first (natural order).
// ---------------------------------------------------------------------------
__global__ __launch_bounds__(256) void stats_kernel(
    const unsigned short* __restrict__ q_hi, const unsigned short* __restrict__ q_lo,
    const unsigned short* __restrict__ k_hi, const unsigned short* __restrict__ k_lo,
    float* __restrict__ m_st, float* __restrict__ il_st)
{
    __shared__ float lm[4][16];
    __shared__ float ll[4][16];
    int tid = threadIdx.x;
    int wave = tid >> 6, lane = tid & 63;
    int c15 = lane & 15, kg = lane >> 4;
    int b = blockIdx.y;
    int s_base = blockIdx.x * 16;

    // A fragments: k rows (persist whole kernel, same for all 4 waves; L1-hot)
    short8 a_h[4], a_l[4];
    {
        int s = s_base + c15;
        const unsigned short* kr = k_hi + ((size_t)(b * Tn + s)) * Hn + kg * 8;
        const unsigned short* krl = k_lo + ((size_t)(b * Tn + s)) * Hn + kg * 8;
#pragma unroll
        for (int st = 0; st < 4; st++) {
            a_h[st] = *(const short8*)(kr + st * 32);
            a_l[st] = *(const short8*)(krl + st * 32);
        }
    }
    float m[4], l[4];
#pragma unroll
    for (int r = 0; r < 4; r++) { m[r] = -3.0e38f; l[r] = 0.0f; }

    for (int tt = s_base + wave * 16; tt < Tn; tt += 64) {
        int t = tt + c15;   // this lane's column (n index)
        const unsigned short* qr = q_hi + ((size_t)(b * Tn + t)) * Hn + kg * 8;
        const unsigned short* qrl = q_lo + ((size_t)(b * Tn + t)) * Hn + kg * 8;
        float4v acc1 = (float4v)0.0f, acc2 = (float4v)0.0f, acc3 = (float4v)0.0f;
#pragma unroll
        for (int st = 0; st < 4; st++) {
            short8 bh = *(const short8*)(qr + st * 32);
            short8 bl = *(const short8*)(qrl + st * 32);
            acc1 = MFMA16(a_h[st], bh, acc1);
            acc2 = MFMA16(a_h[st], bl, acc2);
            acc3 = MFMA16(a_l[st], bh, acc3);
        }
#pragma unroll
        for (int r = 0; r < 4; r++) {
            float attv = (acc1[r] + acc2[r] + acc3[r]) * SQRTH;
            int s_row = s_base + kg * 4 + r;
            bool valid = (t >= s_row);
            float cand = valid ? attv : -3.0e38f;
            float mn = fmaxf(m[r], cand);
            l[r] = l[r] * __expf(m[r] - mn) + (valid ? __expf(attv - mn) : 0.0f);
            m[r] = mn;
        }
    }
    // merge t-subsets across the 16 lanes sharing kg
#pragma unroll
    for (int mask = 1; mask < 16; mask <<= 1) {
#pragma unroll
        for (int r = 0; r < 4; r++) {
            float mo = __shfl_xor(m[r], mask);
            float lo2 = __shfl_xor(l[r], mask);
            float mn = fmaxf(m[r], mo);
            l[r] = l[r] * __expf(m[r] - mn) + lo2 * __expf(mo - mn);
            m[r] = mn;
        }
    }
    if (c15 == 0) {
#pragma unroll
        for (int r = 0; r < 4; r++) {
            lm[wave][kg * 4 + r] = m[r];
            ll[wave][kg * 4 + r] = l[r];
        }
    }
    __syncthreads();
    if (tid < 16) {
        float mf = lm[0][tid];
#pragma unroll
        for (int w = 1; w < 4; w++) mf = fmaxf(mf, lm[w][tid]);
        float lf = 0.0f;
#pragma unroll
        for (int w = 0; w < 4; w++) lf += ll[w][tid] * __expf(lm[w][tid] - mf);
        int s = s_base + tid;
        m_st[b * Tn + s] = mf;
        il_st[b * Tn + s] = 1.0f / lf;
    }
}

// ---------------------------------------------------------------------------
// Kernel 3: output. Block (4 waves) per (b, 16-row t-tile). Waves split the
// s-tile loop (stride 4), accumulate private fp32 partials, LDS reduction,
// coalesced float4 store. grid (128, B); heavy tiles dispatched first.
// ---------------------------------------------------------------------------
__global__ __launch_bounds__(256) void out_kernel(
    const unsigned short* __restrict__ q_hi, const unsigned short* __restrict__ q_lo,
    const unsigned short* __restrict__ k_hi, const unsigned short* __restrict__ k_lo,
    const unsigned short* __restrict__ vT,
    const float* __restrict__ m_st, const float* __restrict__ il_st,
    float* __restrict__ out)
{
    __shared__ __align__(16) unsigned short pbuf[4][16][40];
    __shared__ __align__(16) float obuf[4][16][128];   // 32 KB
    int tid = threadIdx.x;
    int wave = tid >> 6, lane = tid & 63;
    int c15 = lane & 15, kg = lane >> 4;
    int b = blockIdx.y;
    int tt = (int)gridDim.x - 1 - (int)blockIdx.x;   // heavy (high t) first
    int t_base = tt * 16;

    // A fragments: q rows (persist; same for all 4 waves, L1-hot)
    short8 qa_h[4], qa_l[4];
    {
        int t = t_base + c15;
        const unsigned short* qr = q_hi + ((size_t)(b * Tn + t)) * Hn + kg * 8;
        const unsigned short* qrl = q_lo + ((size_t)(b * Tn + t)) * Hn + kg * 8;
#pragma unroll
        for (int st = 0; st < 4; st++) {
            qa_h[st] = *(const short8*)(qr + st * 32);
            qa_l[st] = *(const short8*)(qrl + st * 32);
        }
    }
    float4v oacc[8];
#pragma unroll
    for (int i = 0; i < 8; i++) oacc[i] = (float4v)0.0f;

    int ns = (t_base + 15) / 32 + 1;
    for (int ss = wave; ss < ns; ss += 4) {
        int s0 = ss * 32;
#pragma unroll
        for (int half = 0; half < 2; half++) {
            int s16 = s0 + half * 16;
            int s = s16 + c15;
            const unsigned short* kr = k_hi + ((size_t)(b * Tn + s)) * Hn + kg * 8;
            const unsigned short* krl = k_lo + ((size_t)(b * Tn + s)) * Hn + kg * 8;
            float4v acc1 = (float4v)0.0f, acc2 = (float4v)0.0f, acc3 = (float4v)0.0f;
#pragma unroll
            for (int st = 0; st < 4; st++) {
                short8 bh = *(const short8*)(kr + st * 32);
                short8 bl = *(const short8*)(krl + st * 32);
                acc1 = MFMA16(qa_h[st], bh, acc1);
                acc2 = MFMA16(qa_h[st], bl, acc2);
                acc3 = MFMA16(qa_l[st], bh, acc3);
            }
            float msv = m_st[b * Tn + s16 + c15];
            float ilv = il_st[b * Tn + s16 + c15];
#pragma unroll
            for (int r = 0; r < 4; r++) {
                int t = t_base + kg * 4 + r;
                float attv = (acc1[r] + acc2[r] + acc3[r]) * SQRTH;
                float p = (t >= s16 + c15) ? __expf(attv - msv) * ilv : 0.0f;
                pbuf[wave][kg * 4 + r][c15 + half * 16] = f2bf(p);
            }
        }
        // C-layout -> A-layout via LDS (wave-internal, DS pipe is in-order)
        short8 pa = *(const short8*)&pbuf[wave][c15][kg * 8];
#pragma unroll
        for (int nt = 0; nt < 8; nt++) {
            int h = nt * 16 + c15;
            short8 vb = *(const short8*)(vT + ((size_t)(b * Hn + h)) * Tn + s0 + kg * 8);
            oacc[nt] = MFMA16(pa, vb, oacc[nt]);
        }
    }
    // dump wave partials: oacc[nt][r] is (t_local = kg*4+r, h = nt*16+c15)
#pragma unroll
    for (int nt = 0; nt < 8; nt++) {
#pragma unroll
        for (int r = 0; r < 4; r++) {
            obuf[wave][kg * 4 + r][nt * 16 + c15] = oacc[nt][r];
        }
    }
    __syncthreads();
    // block reduction + coalesced store: 2048 floats, 8 per thread
    int e0 = tid * 8;
    int tl = e0 >> 7, h0 = e0 & 127;
    float4v r0 = (float4v)0.0f, r1 = (float4v)0.0f;
#pragma unroll
    for (int w = 0; w < 4; w++) {
        r0 += *(const float4v*)&obuf[w][tl][h0];
        r1 += *(const float4v*)&obuf[w][tl][h0 + 4];
    }
    size_t oo = ((size_t)b * Tn + t_base + tl) * Hn + h0;
    *(float4v*)(out + oo) = r0;
    *(float4v*)(out + oo + 4) = r1;
}

// ---------------------------------------------------------------------------
extern "C" void kernel_launch(void* const* d_in, const int* in_sizes, int n_in,
                              void* d_out, int out_size, void* d_ws, size_t ws_size,
                              hipStream_t stream)
{
    (void)in_sizes; (void)n_in; (void)out_size; (void)ws_size;
    const float* x  = (const float*)d_in[0];
    const float* Wk = (const float*)d_in[1];
    const float* Wq = (const float*)d_in[2];
    const float* Wv = (const float*)d_in[3];
    float* out = (float*)d_out;

    const size_t NQ = (size_t)Bn * Tn * Hn;        // 2,097,152
    unsigned short* q_hi = (unsigned short*)d_ws;
    unsigned short* q_lo = q_hi + NQ;
    unsigned short* k_hi = q_lo + NQ;
    unsigned short* k_lo = k_hi + NQ;
    unsigned short* vT   = k_lo + NQ;
    unsigned short* wt_hi = vT + NQ;
    unsigned short* wt_lo = wt_hi + (size_t)3 * Hn * En;
    float* m_st  = (float*)(wt_lo + (size_t)3 * Hn * En);
    float* il_st = m_st + (size_t)Bn * Tn;
    // total ws use: ~21.6 MB

    wtrans_kernel<<<dim3(512, 3), 256, 0, stream>>>(Wq, Wk, Wv, wt_hi, wt_lo);
    proj_kernel<<<dim3(256, 3), 256, 0, stream>>>(x, wt_hi, wt_lo, q_hi, q_lo, k_hi, k_lo, vT);
    stats_kernel<<<dim3(128, Bn), 256, 0, stream>>>(q_hi, q_lo, k_hi, k_lo, m_st, il_st);
    out_kernel<<<dim3(128, Bn), 256, 0, stream>>>(q_hi, q_lo, k_hi, k_lo, vT, m_st, il_st, out);
}